// Round 2
// baseline (450.071 us; speedup 1.0000x reference)
//
#include <hip/hip_runtime.h>
#include <hip/hip_bf16.h>
#include <stdint.h>
#include <stddef.h>

// x [4,2048,4096] f32, W [4096,4096] f32, b [4096] f32 ; out [8192,4096] f32
#define DIN  4096
#define MTOK 8192
#define NOUT 4096
#define KT   64          // 4096 / 64 k-tiles

typedef __attribute__((ext_vector_type(4))) int   i32x4;
typedef __attribute__((ext_vector_type(4))) float f32x4;

// ws layout (bytes)
#define OFF_SUM 0                        // double (zeroed via memset)
#define OFF_F   256                      // float f[8192] = rowmax/127 (pre-wscale)
#define OFF_QX  65536                    // packed qX: [512 mt][64 kt][1024B]
#define OFF_QW  (65536 + (size_t)MTOK*DIN)  // packed qW: [256 nt][64 kt][1024B]

// Packed tile: 16 rows x 64 k (1KB). byte(row,k) = ((k>>4)&3)*256 + row*16 + (k&15)
// == exact mfma_i32_16x16x64_i8 lane order (lane = row + ((k>>4)&3)*16, byte k&15),
// verified by round-1's passing 16x16x64 addressing.

// ---------------- kernel 1: sum |W| in fp64 ----------------
__global__ __launch_bounds__(256) void k_sumabs(const float* __restrict__ W,
                                                double* __restrict__ sum) {
  int idx = blockIdx.x * 256 + threadIdx.x;      // 2048 blocks
  const f32x4* W4 = (const f32x4*)W;
  double s = 0.0;
#pragma unroll
  for (int i = 0; i < 8; ++i) {
    f32x4 v = W4[idx + i * 524288];
    s += (double)fabsf(v[0]) + (double)fabsf(v[1]) +
         (double)fabsf(v[2]) + (double)fabsf(v[3]);
  }
#pragma unroll
  for (int off = 32; off > 0; off >>= 1) s += __shfl_xor(s, off);
  __shared__ double wsum[4];
  int lane = threadIdx.x & 63, w = threadIdx.x >> 6;
  if (lane == 0) wsum[w] = s;
  __syncthreads();
  if (threadIdx.x == 0) atomicAdd(sum, wsum[0] + wsum[1] + wsum[2] + wsum[3]);
}

// ---------------- kernel 2: fused quantize W & X into packed layout ----------
// blocks [0,256): W rows blk*16 ; blocks [256,768): x tokens (blk-256)*16
__global__ __launch_bounds__(256) void k_quant(const float* __restrict__ x,
                                               const float* __restrict__ W,
                                               const double* __restrict__ sum,
                                               char* __restrict__ qX,
                                               char* __restrict__ qW,
                                               float* __restrict__ f) {
  __shared__ float sval[16];
  __shared__ float red[16][4];
  const int blk = blockIdx.x;
  const int t = threadIdx.x;
  const bool isW = (blk < 256);
  const float* src;
  char* dst;
  if (isW) {
    src = W + (size_t)blk * 16 * DIN;
    dst = qW + (size_t)blk * 65536;
  } else {
    src = x + (size_t)(blk - 256) * 16 * DIN;
    dst = qX + (size_t)(blk - 256) * 65536;
  }
  float lo, hi;
  if (isW) {
    if (t < 16) {
      float s = (float)(*sum * (1.0 / 16777216.0));
      if (s < 1e-6f) s = 1e-6f;
      sval[t] = s;                       // W path divides by s
    }
    lo = -1.f; hi = 1.f;
  } else {
    // phase 1: per-row absmax (row = i>>2, compile-time)
    const f32x4* sv = (const f32x4*)src;
    float rmax[16];
#pragma unroll
    for (int r = 0; r < 16; ++r) rmax[r] = 0.f;
#pragma unroll
    for (int i = 0; i < 64; ++i) {
      f32x4 v = sv[i * 256 + t];
      float mm = fmaxf(fmaxf(fabsf(v[0]), fabsf(v[1])),
                       fmaxf(fabsf(v[2]), fabsf(v[3])));
      rmax[i >> 2] = fmaxf(rmax[i >> 2], mm);
    }
    const int lane = t & 63, w = t >> 6;
#pragma unroll
    for (int r = 0; r < 16; ++r) {
      float v = rmax[r];
#pragma unroll
      for (int off = 32; off > 0; off >>= 1) v = fmaxf(v, __shfl_xor(v, off));
      if (lane == 0) red[r][w] = v;
    }
    __syncthreads();
    if (t < 16) {
      float m = fmaxf(fmaxf(red[t][0], red[t][1]), fmaxf(red[t][2], red[t][3]));
      m = fmaxf(m, 1e-6f);
      sval[t] = 127.0f / m;              // X path multiplies by 127/max
      f[(blk - 256) * 16 + t] = m * (1.0f / 127.0f);
    }
    lo = -128.f; hi = 127.f;
  }
  __syncthreads();
  // phase 2: quantize + write packed, write-linear (o = i*1024 + t*4)
#pragma unroll 4
  for (int i = 0; i < 64; ++i) {
    const int o = i * 1024 + t * 4;
    const int row = (t >> 2) & 15;
    const int k = i * 64 + (t >> 6) * 16 + (t & 3) * 4;
    f32x4 v = *(const f32x4*)(src + (size_t)row * DIN + k);
    float s = sval[row];
    int q0, q1, q2, q3;
    if (isW) {
      q0 = (int)fminf(fmaxf(rintf(v[0] / s), lo), hi);
      q1 = (int)fminf(fmaxf(rintf(v[1] / s), lo), hi);
      q2 = (int)fminf(fmaxf(rintf(v[2] / s), lo), hi);
      q3 = (int)fminf(fmaxf(rintf(v[3] / s), lo), hi);
    } else {
      q0 = (int)fminf(fmaxf(rintf(v[0] * s), lo), hi);
      q1 = (int)fminf(fmaxf(rintf(v[1] * s), lo), hi);
      q2 = (int)fminf(fmaxf(rintf(v[2] * s), lo), hi);
      q3 = (int)fminf(fmaxf(rintf(v[3] * s), lo), hi);
    }
    uint32_t pk = (uint32_t)(q0 & 255) | ((uint32_t)(q1 & 255) << 8) |
                  ((uint32_t)(q2 & 255) << 16) | ((uint32_t)(q3 & 255) << 24);
    *(uint32_t*)(dst + o) = pk;
  }
}

// ---------------- kernel 3: i8 GEMM, 256x256 tile, depth-2 counted-vmcnt ----
__device__ __forceinline__ void gload16(const void* g, void* l) {
  __builtin_amdgcn_global_load_lds(
      (const __attribute__((address_space(1))) void*)g,
      (__attribute__((address_space(3))) void*)l, 16, 0, 0);
}

__global__ __launch_bounds__(512, 2) void k_gemm(const char* __restrict__ qX,
                                                 const char* __restrict__ qW,
                                                 const float* __restrict__ f,
                                                 const double* __restrict__ sum,
                                                 const float* __restrict__ bias,
                                                 float* __restrict__ out) {
  // bijective XCD swizzle: concurrent 32 blocks per XCD form a 4m x 8n panel
  const int bid = blockIdx.x;                 // 512 blocks
  const int xcd = bid & 7, slot = bid >> 3;   // slot 0..63
  const int pass = slot >> 5, q = slot & 31;
  const int mm = q >> 3, nn = q & 7;
  const int pm = xcd >> 1, pn = xcd & 1;
  const int bmi = pass * 16 + pm * 4 + mm;    // 0..31
  const int bni = pn * 8 + nn;                // 0..15
  const int mt0 = bmi * 16;                   // first m-tile16
  const int nt0 = bni * 16;

  __shared__ __align__(16) char lds[4][2][16384];  // [buf][A/B][16 tiles x 1KB]

  const int t = threadIdx.x;
  const int lane = t & 63;
  const int w = t >> 6;                       // wave 0..7
  const int wm = w >> 2, wn = w & 3;          // 2 x 4 wave grid (128 x 64 per wave)

  // staging sources: wave w stages A tiles {w, w+8}, B tiles {w, w+8}
  const char* gA0 = qX + ((size_t)(mt0 + w) * 64) * 1024 + lane * 16;
  const char* gA1 = qX + ((size_t)(mt0 + w + 8) * 64) * 1024 + lane * 16;
  const char* gB0 = qW + ((size_t)(nt0 + w) * 64) * 1024 + lane * 16;
  const char* gB1 = qW + ((size_t)(nt0 + w + 8) * 64) * 1024 + lane * 16;

#define STAGE(buf, kt) do {                                     \
    gload16(gA0 + (size_t)(kt) * 1024, &lds[buf][0][w * 1024]);        \
    gload16(gA1 + (size_t)(kt) * 1024, &lds[buf][0][(w + 8) * 1024]);  \
    gload16(gB0 + (size_t)(kt) * 1024, &lds[buf][1][w * 1024]);        \
    gload16(gB1 + (size_t)(kt) * 1024, &lds[buf][1][(w + 8) * 1024]);  \
  } while (0)

  i32x4 acc[8][4] = {};

  auto compute = [&](int buf) {
    const char* bA = &lds[buf][0][wm * 8192 + lane * 16];
    const char* bB = &lds[buf][1][wn * 4096 + lane * 16];
    i32x4 a[8], b[4];
#pragma unroll
    for (int i = 0; i < 8; ++i) a[i] = *(const i32x4*)(bA + i * 1024);
#pragma unroll
    for (int j = 0; j < 4; ++j) b[j] = *(const i32x4*)(bB + j * 1024);
    __builtin_amdgcn_s_setprio(1);
#pragma unroll
    for (int i = 0; i < 8; ++i)
#pragma unroll
      for (int j = 0; j < 4; ++j)
        acc[i][j] = __builtin_amdgcn_mfma_i32_16x16x64_i8(a[i], b[j], acc[i][j], 0, 0, 0);
    __builtin_amdgcn_s_setprio(0);
  };

  STAGE(0, 0);
  STAGE(1, 1);
  for (int kt = 0; kt < KT - 2; ++kt) {
    STAGE((kt + 2) & 3, kt + 2);
    asm volatile("s_waitcnt vmcnt(8)" ::: "memory");  // kt's 4 loads done; 8 in flight
    __builtin_amdgcn_s_barrier();
    asm volatile("" ::: "memory");
    compute(kt & 3);
  }
  asm volatile("s_waitcnt vmcnt(4)" ::: "memory");
  __builtin_amdgcn_s_barrier();
  asm volatile("" ::: "memory");
  compute((KT - 2) & 3);
  asm volatile("s_waitcnt vmcnt(0)" ::: "memory");
  __builtin_amdgcn_s_barrier();
  asm volatile("" ::: "memory");
  compute((KT - 1) & 3);

  // epilogue: out[m][n] = acc * (f[m]*wscale) + bias[n]
  float wsc = (float)(*sum * (1.0 / 16777216.0));
  if (wsc < 1e-6f) wsc = 1e-6f;
  const int col0 = bni * 256 + wn * 64 + (lane & 15);
  const int row0 = bmi * 256 + wm * 128 + ((lane >> 4) << 2);
  float bj[4];
#pragma unroll
  for (int j = 0; j < 4; ++j) bj[j] = bias[col0 + j * 16];
#pragma unroll
  for (int i = 0; i < 8; ++i) {
#pragma unroll
    for (int qr = 0; qr < 4; ++qr) {
      const int m = row0 + i * 16 + qr;
      const float fm = f[m] * wsc;
      float* orow = out + (size_t)m * NOUT;
#pragma unroll
      for (int j = 0; j < 4; ++j)
        orow[col0 + j * 16] = (float)acc[i][j][qr] * fm + bj[j];
    }
  }
#undef STAGE
}

extern "C" void kernel_launch(void* const* d_in, const int* in_sizes, int n_in,
                              void* d_out, int out_size, void* d_ws, size_t ws_size,
                              hipStream_t stream) {
  const float* x    = (const float*)d_in[0];
  const float* W    = (const float*)d_in[1];
  const float* bias = (const float*)d_in[2];
  float* out = (float*)d_out;
  char* ws = (char*)d_ws;

  double* sum = (double*)(ws + OFF_SUM);
  float* f    = (float*)(ws + OFF_F);
  char* qX    = ws + OFF_QX;
  char* qW    = ws + OFF_QW;

  hipMemsetAsync(d_ws, 0, 256, stream);
  k_sumabs<<<2048, 256, 0, stream>>>(W, sum);
  k_quant<<<768, 256, 0, stream>>>(x, W, sum, qX, qW, f);
  k_gemm<<<512, 512, 0, stream>>>(qX, qW, f, sum, bias, out);
}

// Round 4
// 417.940 us; speedup vs baseline: 1.0769x; 1.0769x over previous
//
#include <hip/hip_runtime.h>
#include <hip/hip_bf16.h>
#include <stdint.h>
#include <stddef.h>

// x [4,2048,4096] f32, W [4096,4096] f32, b [4096] f32 ; out [8192,4096] f32
#define DIN  4096
#define MTOK 8192
#define NOUT 4096
#define KT   64          // 4096 / 64 k-tiles

typedef __attribute__((ext_vector_type(4))) int   i32x4;
typedef __attribute__((ext_vector_type(4))) float f32x4;

// ws layout (bytes)
#define OFF_SUM 0                        // double (zeroed via memset)
#define OFF_F   256                      // float f[8192] = rowmax/127 (pre-wscale)
#define OFF_QX  65536                    // packed qX: [512 mt][64 kt][1024B]
#define OFF_QW  (65536 + (size_t)MTOK*DIN)  // packed qW: [256 nt][64 kt][1024B]

// Packed tile: 16 rows x 64 k (1KB). byte(row,k) = ((k>>4)&3)*256 + row*16 + (k&15)
// == exact mfma_i32_16x16x64_i8 lane order (verified: rounds 1-2 pass).

// ---------------- kernel 1: sum |W| in fp64 ----------------
__global__ __launch_bounds__(256) void k_sumabs(const float* __restrict__ W,
                                                double* __restrict__ sum) {
  int idx = blockIdx.x * 256 + threadIdx.x;      // 2048 blocks
  const f32x4* W4 = (const f32x4*)W;
  double s = 0.0;
#pragma unroll
  for (int i = 0; i < 8; ++i) {
    f32x4 v = W4[idx + i * 524288];
    s += (double)fabsf(v[0]) + (double)fabsf(v[1]) +
         (double)fabsf(v[2]) + (double)fabsf(v[3]);
  }
#pragma unroll
  for (int off = 32; off > 0; off >>= 1) s += __shfl_xor(s, off);
  __shared__ double wsum[4];
  int lane = threadIdx.x & 63, w = threadIdx.x >> 6;
  if (lane == 0) wsum[w] = s;
  __syncthreads();
  if (threadIdx.x == 0) atomicAdd(sum, wsum[0] + wsum[1] + wsum[2] + wsum[3]);
}

// ---------------- kernel 2: fused single-pass quantize (one wave per row) ----
// blocks [0,512): W rows blk*8+w ; blocks [512,1536): tokens (blk-512)*8+w
__global__ __launch_bounds__(512) void k_quantall(const float* __restrict__ x,
                                                  const float* __restrict__ W,
                                                  const double* __restrict__ sum,
                                                  char* __restrict__ qX,
                                                  char* __restrict__ qW,
                                                  float* __restrict__ f) {
  const int t = threadIdx.x;
  const int w = t >> 6, lane = t & 63;
  const int blk = blockIdx.x;
  const bool isW = (blk < 512);
  const int row = isW ? (blk * 8 + w) : ((blk - 512) * 8 + w);
  const float* src = (isW ? W : x) + (size_t)row * DIN + lane * 64;

  // load 64 floats (lane-contiguous 256B window; L1 absorbs the 16-inst sweep)
  f32x4 v[16];
#pragma unroll
  for (int i = 0; i < 16; ++i) v[i] = ((const f32x4*)src)[i];

  float s;
  if (isW) {
    float ws = (float)(*sum * (1.0 / 16777216.0));
    if (ws < 1e-6f) ws = 1e-6f;
    s = ws;
  } else {
    float m = 0.f;
#pragma unroll
    for (int i = 0; i < 16; ++i)
      m = fmaxf(m, fmaxf(fmaxf(fabsf(v[i][0]), fabsf(v[i][1])),
                         fmaxf(fabsf(v[i][2]), fabsf(v[i][3]))));
#pragma unroll
    for (int off = 32; off > 0; off >>= 1) m = fmaxf(m, __shfl_xor(m, off));
    m = fmaxf(m, 1e-6f);
    if (lane == 0) f[row] = m * (1.0f / 127.0f);
    s = 127.0f / m;
  }

  char* dst = (isW ? qW : qX) + (size_t)(row >> 4) * 65536 +
              (size_t)lane * 1024 + (row & 15) * 16;
#pragma unroll
  for (int c = 0; c < 4; ++c) {
    i32x4 pk;
#pragma unroll
    for (int wd = 0; wd < 4; ++wd) {
      f32x4 u = v[c * 4 + wd];
      int q0, q1, q2, q3;
      if (isW) {
        q0 = (int)fminf(fmaxf(rintf(u[0] / s), -1.f), 1.f);
        q1 = (int)fminf(fmaxf(rintf(u[1] / s), -1.f), 1.f);
        q2 = (int)fminf(fmaxf(rintf(u[2] / s), -1.f), 1.f);
        q3 = (int)fminf(fmaxf(rintf(u[3] / s), -1.f), 1.f);
      } else {
        q0 = (int)fminf(fmaxf(rintf(u[0] * s), -128.f), 127.f);
        q1 = (int)fminf(fmaxf(rintf(u[1] * s), -128.f), 127.f);
        q2 = (int)fminf(fmaxf(rintf(u[2] * s), -128.f), 127.f);
        q3 = (int)fminf(fmaxf(rintf(u[3] * s), -128.f), 127.f);
      }
      pk[wd] = (int)((uint32_t)(q0 & 255) | ((uint32_t)(q1 & 255) << 8) |
                     ((uint32_t)(q2 & 255) << 16) | ((uint32_t)(q3 & 255) << 24));
    }
    *(i32x4*)(dst + c * 256) = pk;
  }
}

// ---------------- kernel 3: i8 GEMM, 256x256, T3/T4 two-barrier phases -------
__device__ __forceinline__ void gload16(const void* g, void* l) {
  __builtin_amdgcn_global_load_lds(
      (const __attribute__((address_space(1))) void*)g,
      (__attribute__((address_space(3))) void*)l, 16, 0, 0);
}

__global__ __launch_bounds__(512, 2) void k_gemm(const char* __restrict__ qX,
                                                 const char* __restrict__ qW,
                                                 const float* __restrict__ f,
                                                 const double* __restrict__ sum,
                                                 const float* __restrict__ bias,
                                                 float* __restrict__ out) {
  const int bid = blockIdx.x;                 // 512 blocks
  const int xcd = bid & 7, slot = bid >> 3;
  const int pass = slot >> 5, q = slot & 31;
  const int mm = q >> 3, nn = q & 7;
  const int pm = xcd >> 1, pn = xcd & 1;
  const int bmi = pass * 16 + pm * 4 + mm;    // 0..31
  const int bni = pn * 8 + nn;                // 0..15
  const int mt0 = bmi * 16;
  const int nt0 = bni * 16;

  __shared__ __align__(16) char lds[4][2][16384];  // [buf][A/B][16 tiles x 1KB]

  const int t = threadIdx.x;
  const int lane = t & 63;
  const int w = t >> 6;
  const int wm = w >> 2, wn = w & 3;          // 2 x 4 wave grid (128 x 64 per wave)

  const char* gA0 = qX + ((size_t)(mt0 + w) * 64) * 1024 + lane * 16;
  const char* gA1 = qX + ((size_t)(mt0 + w + 8) * 64) * 1024 + lane * 16;
  const char* gB0 = qW + ((size_t)(nt0 + w) * 64) * 1024 + lane * 16;
  const char* gB1 = qW + ((size_t)(nt0 + w + 8) * 64) * 1024 + lane * 16;

#define STAGE(buf, kt) do {                                            \
    gload16(gA0 + (size_t)(kt) * 1024, &lds[buf][0][w * 1024]);        \
    gload16(gA1 + (size_t)(kt) * 1024, &lds[buf][0][(w + 8) * 1024]);  \
    gload16(gB0 + (size_t)(kt) * 1024, &lds[buf][1][w * 1024]);        \
    gload16(gB1 + (size_t)(kt) * 1024, &lds[buf][1][(w + 8) * 1024]);  \
  } while (0)

#define LOADFRAGS(buf) do {                                            \
    const char* bA = &lds[buf][0][wm * 8192 + lane * 16];              \
    const char* bB = &lds[buf][1][wn * 4096 + lane * 16];              \
    _Pragma("unroll")                                                  \
    for (int i = 0; i < 8; ++i) a[i] = *(const i32x4*)(bA + i * 1024); \
    _Pragma("unroll")                                                  \
    for (int j = 0; j < 4; ++j) b[j] = *(const i32x4*)(bB + j * 1024); \
  } while (0)

#define MFMAS do {                                                     \
    __builtin_amdgcn_s_setprio(1);                                     \
    _Pragma("unroll")                                                  \
    for (int i = 0; i < 8; ++i)                                        \
      _Pragma("unroll")                                                \
      for (int j = 0; j < 4; ++j)                                      \
        acc[i][j] = __builtin_amdgcn_mfma_i32_16x16x64_i8(a[i], b[j], acc[i][j], 0, 0, 0); \
    __builtin_amdgcn_s_setprio(0);                                     \
  } while (0)

  i32x4 acc[8][4] = {};
  i32x4 a[8], b[4];

  STAGE(0, 0);
  STAGE(1, 1);
  asm volatile("s_waitcnt vmcnt(4)" ::: "memory");   // buf0 writes done
  __builtin_amdgcn_s_barrier();

  for (int kt = 0; kt < KT - 2; ++kt) {
    LOADFRAGS(kt & 3);                    // issue ds_reads (fly over barrier)
    STAGE((kt + 2) & 3, kt + 2);          // depth-2 prefetch stays in flight
    __builtin_amdgcn_s_barrier();
    asm volatile("s_waitcnt lgkmcnt(0)" ::: "memory");
    __builtin_amdgcn_sched_barrier(0);
    MFMAS;
    asm volatile("s_waitcnt vmcnt(4)" ::: "memory");  // buf[kt+1] ready; kt+2 in flight
    __builtin_amdgcn_s_barrier();
  }
  // kt = KT-2
  LOADFRAGS((KT - 2) & 3);
  __builtin_amdgcn_s_barrier();
  asm volatile("s_waitcnt lgkmcnt(0)" ::: "memory");
  __builtin_amdgcn_sched_barrier(0);
  MFMAS;
  asm volatile("s_waitcnt vmcnt(0)" ::: "memory");    // last buf ready
  __builtin_amdgcn_s_barrier();
  // kt = KT-1
  LOADFRAGS((KT - 1) & 3);
  asm volatile("s_waitcnt lgkmcnt(0)" ::: "memory");
  __builtin_amdgcn_sched_barrier(0);
  MFMAS;

  // epilogue: out[m][n] = acc * (f[m]*wscale) + bias[n]
  float wsc = (float)(*sum * (1.0 / 16777216.0));
  if (wsc < 1e-6f) wsc = 1e-6f;
  const int col0 = bni * 256 + wn * 64 + (lane & 15);
  const int row0 = bmi * 256 + wm * 128 + ((lane >> 4) << 2);
  float bj[4];
#pragma unroll
  for (int j = 0; j < 4; ++j) bj[j] = bias[col0 + j * 16];
#pragma unroll
  for (int i = 0; i < 8; ++i) {
#pragma unroll
    for (int qr = 0; qr < 4; ++qr) {
      const int m = row0 + i * 16 + qr;
      const float fm = f[m] * wsc;
      float* orow = out + (size_t)m * NOUT;
#pragma unroll
      for (int j = 0; j < 4; ++j)
        orow[col0 + j * 16] = (float)acc[i][j][qr] * fm + bj[j];
    }
  }
#undef STAGE
#undef LOADFRAGS
#undef MFMAS
}

extern "C" void kernel_launch(void* const* d_in, const int* in_sizes, int n_in,
                              void* d_out, int out_size, void* d_ws, size_t ws_size,
                              hipStream_t stream) {
  const float* x    = (const float*)d_in[0];
  const float* W    = (const float*)d_in[1];
  const float* bias = (const float*)d_in[2];
  float* out = (float*)d_out;
  char* ws = (char*)d_ws;

  double* sum = (double*)(ws + OFF_SUM);
  float* f    = (float*)(ws + OFF_F);
  char* qX    = ws + OFF_QX;
  char* qW    = ws + OFF_QW;

  hipMemsetAsync(d_ws, 0, 256, stream);
  k_sumabs<<<2048, 256, 0, stream>>>(W, sum);
  k_quantall<<<1536, 512, 0, stream>>>(x, W, sum, qX, qW, f);
  k_gemm<<<512, 512, 0, stream>>>(qX, qW, f, sum, bias, out);
}